// Round 10
// baseline (135.223 us; speedup 1.0000x reference)
//
#include <hip/hip_runtime.h>

// Round 10: R9 geometry (128x32 tile, 1024 blocks) with stage-1 load-issue
// reordering: halo loads issue FIRST (vmcnt retires in order, so the wait for
// center batch-0 implies halo has landed -> halo processed right after batch-0
// with zero extra wait; previously halo latency was fully exposed at the
// barrier). Also D/Su/St computed in f32 (exact for ints <= 765) saving cvts.
// Numerics identical to R6/R9 (exact int pipeline, absmax 0 proven).

typedef unsigned short us4 __attribute__((ext_vector_type(4)));

constexpr int Bn = 16, Hn = 512, Wn = 512;
constexpr int TX = 128, TY = 32;
constexpr int GR = TY + 4;    // 36 gray rows (halo 2)
constexpr int GCS = 136;      // gray row stride (ushort); used cols 2..133
constexpr int MR = TY + 2;    // 34 mask rows (halo 1)
constexpr int MCS = 136;      // mask stride (uchar); used cols 3..132
constexpr int NBLK = (Wn / TX) * (Hn / TY) * Bn;   // 4*16*16 = 1024

__device__ __forceinline__ float u8q(float v) {
    return floorf(fminf(fmaxf(v * 255.0f, 0.0f), 255.0f));
}
__device__ __forceinline__ int reflect101(int i, int n) {
    if (i < 0) return -i;
    if (i >= n) return 2 * n - 2 - i;
    return i;
}
__device__ __forceinline__ int gray1(float r, float g, float b) {
    return (int)rintf((0.299f * r + 0.587f * g) + 0.114f * b);
}
__device__ __forceinline__ int grayq(float r, float g, float b) {
    return gray1(u8q(r), u8q(g), u8q(b));
}
__device__ __forceinline__ int iabs(int v) { return v < 0 ? -v : v; }
__device__ __forceinline__ unsigned short pk2(int a, int b) {
    return (unsigned short)(a | (b << 8));
}

__global__ __launch_bounds__(256, 4)
void csl_kernel(const float* __restrict__ pred, const float* __restrict__ tru,
                int2* __restrict__ ws) {
    const int b   = blockIdx.z;
    const int ty0 = blockIdx.y * TY;
    const int tx0 = blockIdx.x * TX;
    const int tid = threadIdx.x;

    __shared__ __align__(16) unsigned short gg[GR][GCS];
    __shared__ unsigned char mk[MR][MCS];
    __shared__ int wss[4], wse[4];

    const size_t chs = (size_t)Hn * Wn;
    const float* pb = pred + (size_t)b * 3 * chs;
    const float* tb = tru  + (size_t)b * 3 * chs;

    int Pk[16];  // per-pixel D | Su<<10 | St<<20, 16 px/thread

    // ================= Stage 1: ISSUE halo loads first =================
    float4 HA, HB, HC, HD4, HE, HF;   // halo vec data
    float hs[12];                     // scalar fallback (image-edge cols)
    int hrow = 0;
    if (tid < 128) {
        const int rh = tid >> 5;
        const int q = tid & 31;
        hrow = (rh < 2) ? rh : rh + TY;            // 0,1,34,35
        const int gy = reflect101(ty0 + hrow - 2, Hn);
        const size_t off = (size_t)gy * Wn + tx0 + 4 * q;
        HA  = *(const float4*)(pb + off);
        HB  = *(const float4*)(pb + chs + off);
        HC  = *(const float4*)(pb + 2 * chs + off);
        HD4 = *(const float4*)(tb + off);
        HE  = *(const float4*)(tb + chs + off);
        HF  = *(const float4*)(tb + 2 * chs + off);
    } else if (tid < 128 + 2 * GR) {               // 72 threads: halo cols
        const int t = tid - 128;
        hrow = t >> 1;                             // 0..35
        const int side = t & 1;
        const int gy = reflect101(ty0 + hrow - 2, Hn);
        const size_t rowo = (size_t)gy * Wn;
        const bool vec = (side == 0) ? (tx0 > 0) : (tx0 + TX < Wn);
        if (vec) {
            const size_t off = rowo + ((side == 0) ? (tx0 - 4) : (tx0 + TX));
            HA  = *(const float4*)(pb + off);
            HB  = *(const float4*)(pb + chs + off);
            HC  = *(const float4*)(pb + 2 * chs + off);
            HD4 = *(const float4*)(tb + off);
            HE  = *(const float4*)(tb + chs + off);
            HF  = *(const float4*)(tb + 2 * chs + off);
        } else {
            const size_t oA = (side == 0) ? (rowo + 2) : (rowo + 510);
            const size_t oB = (side == 0) ? (rowo + 1) : (rowo + 509);
            hs[0] = pb[oA]; hs[1] = pb[oA + chs]; hs[2] = pb[oA + 2 * chs];
            hs[3] = tb[oA]; hs[4] = tb[oA + chs]; hs[5] = tb[oA + 2 * chs];
            hs[6]  = pb[oB]; hs[7]  = pb[oB + chs]; hs[8]  = pb[oB + 2 * chs];
            hs[9]  = tb[oB]; hs[10] = tb[oB + chs]; hs[11] = tb[oB + 2 * chs];
        }
    }

    // ---- quantize+gray+Pk for 4 px from 6 float4s ----
    auto proc6 = [&](int pos, const float4& A, const float4& B,
                     const float4& C, const float4& D4, const float4& E,
                     const float4& F, int* pk) {
        const int r = 2 + (pos >> 5);
        const int q = pos & 31;
        const float* af = (const float*)&A; const float* bf = (const float*)&B;
        const float* cf = (const float*)&C; const float* df = (const float*)&D4;
        const float* ef = (const float*)&E; const float* ff = (const float*)&F;
        us4 gw;
        #pragma unroll
        for (int i = 0; i < 4; ++i) {
            const float pr = u8q(af[i]), pg = u8q(bf[i]), pl = u8q(cf[i]);
            const float tr_ = u8q(df[i]), tg = u8q(ef[i]), tl = u8q(ff[i]);
            const int gp = gray1(pr, pg, pl), gt = gray1(tr_, tg, tl);
            gw[i] = pk2(gp, gt);
            // exact in f32: operands are integers <= 765
            const float fD  = fabsf(pr - tr_) + fabsf(pg - tg) + fabsf(pl - tl);
            const float fSu = (pr + pg) + pl;
            const float fSt = (tr_ + tg) + tl;
            pk[i] = (int)fD | ((int)fSu << 10) | ((int)fSt << 20);
        }
        *(us4*)&gg[r][4 + 4 * q] = gw;
    };

    // ---- center batch 0 (rows 2..17 of gg): issue 12 loads, process ----
    {
        const int p0 = tid, p1 = tid + 256;
        const size_t o0 = (size_t)(ty0 + (p0 >> 5)) * Wn + tx0 + 4 * (p0 & 31);
        const size_t o1 = (size_t)(ty0 + (p1 >> 5)) * Wn + tx0 + 4 * (p1 & 31);
        const float4 a0 = *(const float4*)(pb + o0);
        const float4 b0 = *(const float4*)(pb + chs + o0);
        const float4 c0 = *(const float4*)(pb + 2 * chs + o0);
        const float4 d0 = *(const float4*)(tb + o0);
        const float4 e0 = *(const float4*)(tb + chs + o0);
        const float4 f0 = *(const float4*)(tb + 2 * chs + o0);
        const float4 a1 = *(const float4*)(pb + o1);
        const float4 b1 = *(const float4*)(pb + chs + o1);
        const float4 c1 = *(const float4*)(pb + 2 * chs + o1);
        const float4 d1 = *(const float4*)(tb + o1);
        const float4 e1 = *(const float4*)(tb + chs + o1);
        const float4 f1 = *(const float4*)(tb + 2 * chs + o1);
        proc6(p0, a0, b0, c0, d0, e0, f0, &Pk[0]);
        proc6(p1, a1, b1, c1, d1, e1, f1, &Pk[4]);
    }

    // ---- process halo NOW: waiting on batch-0 already implied halo landed ----
    if (tid < 128) {
        const int q = tid & 31;
        const float* af = (const float*)&HA; const float* bf = (const float*)&HB;
        const float* cf = (const float*)&HC; const float* df = (const float*)&HD4;
        const float* ef = (const float*)&HE; const float* ff = (const float*)&HF;
        us4 gw;
        #pragma unroll
        for (int i = 0; i < 4; ++i)
            gw[i] = pk2(grayq(af[i], bf[i], cf[i]), grayq(df[i], ef[i], ff[i]));
        *(us4*)&gg[hrow][4 + 4 * q] = gw;
    } else if (tid < 128 + 2 * GR) {
        const int side = (tid - 128) & 1;
        const bool vec = (side == 0) ? (tx0 > 0) : (tx0 + TX < Wn);
        const int c0 = (side == 0) ? 2 : 132;
        if (vec) {
            if (side == 0) {
                gg[hrow][2] = pk2(grayq(HA.z, HB.z, HC.z), grayq(HD4.z, HE.z, HF.z));
                gg[hrow][3] = pk2(grayq(HA.w, HB.w, HC.w), grayq(HD4.w, HE.w, HF.w));
            } else {
                gg[hrow][132] = pk2(grayq(HA.x, HB.x, HC.x), grayq(HD4.x, HE.x, HF.x));
                gg[hrow][133] = pk2(grayq(HA.y, HB.y, HC.y), grayq(HD4.y, HE.y, HF.y));
            }
        } else {
            gg[hrow][c0]     = pk2(grayq(hs[0], hs[1], hs[2]),
                                   grayq(hs[3], hs[4], hs[5]));
            gg[hrow][c0 + 1] = pk2(grayq(hs[6], hs[7], hs[8]),
                                   grayq(hs[9], hs[10], hs[11]));
        }
    }

    // ---- center batch 1 (rows 18..33 of gg) ----
    {
        const int p0 = tid + 512, p1 = tid + 768;
        const size_t o0 = (size_t)(ty0 + (p0 >> 5)) * Wn + tx0 + 4 * (p0 & 31);
        const size_t o1 = (size_t)(ty0 + (p1 >> 5)) * Wn + tx0 + 4 * (p1 & 31);
        const float4 a0 = *(const float4*)(pb + o0);
        const float4 b0 = *(const float4*)(pb + chs + o0);
        const float4 c0 = *(const float4*)(pb + 2 * chs + o0);
        const float4 d0 = *(const float4*)(tb + o0);
        const float4 e0 = *(const float4*)(tb + chs + o0);
        const float4 f0 = *(const float4*)(tb + 2 * chs + o0);
        const float4 a1 = *(const float4*)(pb + o1);
        const float4 b1 = *(const float4*)(pb + chs + o1);
        const float4 c1 = *(const float4*)(pb + 2 * chs + o1);
        const float4 d1 = *(const float4*)(tb + o1);
        const float4 e1 = *(const float4*)(tb + chs + o1);
        const float4 f1 = *(const float4*)(tb + 2 * chs + o1);
        proc6(p0, a0, b0, c0, d0, e0, f0, &Pk[8]);
        proc6(p1, a1, b1, c1, d1, e1, f1, &Pk[12]);
    }
    __syncthreads();

    // ---- Stage 2: int sobel on packed bytes, |sp-st| loss, 2-bit mask codes ----
    int accS = 0;
    auto sob4 = [&](int r, int q, bool center) {
        const int cb = 4 + 4 * q;
        const us4 U = *(const us4*)&gg[r][cb];
        const us4 M = *(const us4*)&gg[r + 1][cb];
        const us4 D = *(const us4*)&gg[r + 2][cb];
        const int ml = gg[r + 1][cb - 1];
        const int mr = gg[r + 1][cb + 4];
        const int m[6] = {ml, M.x, M.y, M.z, M.w, mr};
        const int u[4] = {U.x, U.y, U.z, U.w};
        const int d[4] = {D.x, D.y, D.z, D.w};
        unsigned cw = 0;
        #pragma unroll
        for (int i = 0; i < 4; ++i) {
            const int dxp = (m[i + 2] & 255) - (m[i] & 255);
            const int dyp = (d[i] & 255) - (u[i] & 255);
            const int dxt = (m[i + 2] >> 8) - (m[i] >> 8);
            const int dyt = (d[i] >> 8) - (u[i] >> 8);
            const int np = iabs(dxp) + iabs(dyp);
            const int nt = iabs(dxt) + iabs(dyt);
            const int hp = np >> 1, ht = nt >> 1;
            const int sp = hp + (np & hp & 1);   // RNE(np/2)
            const int st = ht + (nt & ht & 1);
            if (center) accS += iabs(sp - st);
            cw |= ((sp > 10 ? 1u : 0u) | (st > 10 ? 2u : 0u)) << (8 * i);
        }
        *(unsigned*)&mk[r][cb] = cw;
    };
    #pragma unroll
    for (int j = 0; j < 4; ++j) {           // mask rows 0..31
        const int pos = tid + 256 * j;
        const int r = pos >> 5, q = pos & 31;
        sob4(r, q, r >= 1);
    }
    if (tid < 64) {                          // mask rows 32,33
        const int pos = tid + 1024;
        const int r = pos >> 5;
        sob4(r, pos & 31, r == 32);
    } else if (tid < 64 + 2 * MR) {          // 68 threads: edge cols 3 / 132
        const int t = tid - 64;
        const int r = t >> 1;                // 0..33
        const int gc = (t & 1) ? 132 : 3;
        const int l = gg[r + 1][gc - 1], rr = gg[r + 1][gc + 1];
        const int uu = gg[r][gc], dd = gg[r + 2][gc];
        const int np = iabs((rr & 255) - (l & 255)) + iabs((dd & 255) - (uu & 255));
        const int nt = iabs((rr >> 8) - (l >> 8)) + iabs((dd >> 8) - (uu >> 8));
        const int hp = np >> 1, ht = nt >> 1;
        const int sp = hp + (np & hp & 1);
        const int st = ht + (nt & ht & 1);
        mk[r][gc] = (unsigned char)((sp > 10 ? 1u : 0u) | (st > 10 ? 2u : 0u));
    }
    __syncthreads();

    // ---- Stage 3: keep = OR over 3x3 codes; edge loss in int ----
    int accE = 0;
    #pragma unroll
    for (int j = 0; j < 4; ++j) {
        const int pos = tid + 256 * j;
        const int py = pos >> 5;       // 0..31, matches stage-1 ordering
        const int q = pos & 31;
        const int cb = 4 + 4 * q;
        unsigned Lo = 0, Co = 0, Ro = 0;
        #pragma unroll
        for (int d = 0; d < 3; ++d) {
            Lo |= *(const unsigned*)&mk[py + d][cb - 4];
            Co |= *(const unsigned*)&mk[py + d][cb];
            Ro |= *(const unsigned*)&mk[py + d][cb + 4];
        }
        unsigned long long w = (unsigned long long)(Lo >> 24) |
                               ((unsigned long long)Co << 8) |
                               ((unsigned long long)(Ro & 0xFFu) << 40);
        unsigned long long t3 = w | (w >> 8) | (w >> 16);
        const int* Pp = &Pk[4 * j];
        #pragma unroll
        for (int i = 0; i < 4; ++i) {
            const unsigned code = (unsigned)(t3 >> (8 * i)) & 3u;
            const int D = Pp[i] & 1023;
            const int Su = (Pp[i] >> 10) & 1023;
            const int St = Pp[i] >> 20;
            const int s1 = (code & 2u) ? D : Su;
            const int s0 = (code & 2u) ? St : 0;
            accE += (code & 1u) ? s1 : s0;
        }
    }

    // ---- Block reduction -> uncontended partial-sum store ----
    #pragma unroll
    for (int off = 32; off > 0; off >>= 1) {
        accS += __shfl_down(accS, off, 64);
        accE += __shfl_down(accE, off, 64);
    }
    const int wave = tid >> 6, lane = tid & 63;
    if (lane == 0) { wss[wave] = accS; wse[wave] = accE; }
    __syncthreads();
    if (tid == 0) {
        const int ts = (wss[0] + wss[1]) + (wss[2] + wss[3]);
        const int te = (wse[0] + wse[1]) + (wse[2] + wse[3]);
        const int bid = (blockIdx.z * gridDim.y + blockIdx.y) * gridDim.x + blockIdx.x;
        ws[bid] = make_int2(ts, te);
    }
}

__global__ __launch_bounds__(256)
void reduce_kernel(const int2* __restrict__ ws, float* __restrict__ out) {
    const int tid = threadIdx.x;
    int s = 0, e = 0;
    for (int i = tid; i < NBLK; i += 256) {
        const int2 v = ws[i];
        s += v.x; e += v.y;
    }
    double ds = (double)s, de = (double)e;
    #pragma unroll
    for (int off = 32; off > 0; off >>= 1) {
        ds += __shfl_down(ds, off, 64);
        de += __shfl_down(de, off, 64);
    }
    __shared__ double rs[4], re[4];
    const int wave = tid >> 6, lane = tid & 63;
    if (lane == 0) { rs[wave] = ds; re[wave] = de; }
    __syncthreads();
    if (tid == 0) {
        const double ts = (rs[0] + rs[1]) + (rs[2] + rs[3]);
        const double te = (re[0] + re[1]) + (re[2] + re[3]);
        const float inv_s = 1.0f / (255.0f * (float)Bn * (float)Hn * (float)Wn);
        out[0] = (float)ts * inv_s;
        out[1] = (float)te * (inv_s / 3.0f);
    }
}

extern "C" void kernel_launch(void* const* d_in, const int* in_sizes, int n_in,
                              void* d_out, int out_size, void* d_ws, size_t ws_size,
                              hipStream_t stream) {
    const float* pred = (const float*)d_in[0];
    const float* tru  = (const float*)d_in[1];
    float* out = (float*)d_out;
    int2* ws = (int2*)d_ws;   // NBLK int2 partials = 8 KB

    dim3 grid(Wn / TX, Hn / TY, Bn);  // 4 x 16 x 16 = 1024 blocks
    csl_kernel<<<grid, 256, 0, stream>>>(pred, tru, ws);
    reduce_kernel<<<1, 256, 0, stream>>>(ws, out);
}

// Round 11
// 125.206 us; speedup vs baseline: 1.0800x; 1.0800x over previous
//
#include <hip/hip_runtime.h>

// Round 11: restore the R6 champion exactly (best measured: bench 125.2us;
// 128x16 tile, 2048 blocks = 2 naturally-staggered occupancy rounds,
// launch_bounds(256,4), no spills) + one safe trim: D/Su/St computed in f32
// from already-quantized values (exact for integers <= 765), saving cvt+int
// ops in stage 1. R10's halo-first reorder is reverted (it spilled: 16.4MB
// scratch writes). R5/R10 lesson: never pressure the RA around the 12-float4
// in-flight batch.

typedef unsigned short us4 __attribute__((ext_vector_type(4)));

constexpr int Bn = 16, Hn = 512, Wn = 512;
constexpr int TX = 128, TY = 16;
constexpr int GR = TY + 4;    // 20 gray rows (halo 2)
constexpr int GCS = 136;      // gray row stride (ushort); used cols 2..133
constexpr int MR = TY + 2;    // 18 mask rows (halo 1)
constexpr int MCS = 136;      // mask stride (uchar); used cols 3..132
constexpr int NBLK = (Wn / TX) * (Hn / TY) * Bn;   // 2048

__device__ __forceinline__ float u8q(float v) {
    return floorf(fminf(fmaxf(v * 255.0f, 0.0f), 255.0f));
}
__device__ __forceinline__ int reflect101(int i, int n) {
    if (i < 0) return -i;
    if (i >= n) return 2 * n - 2 - i;
    return i;
}
__device__ __forceinline__ int gray1(float r, float g, float b) {
    return (int)rintf((0.299f * r + 0.587f * g) + 0.114f * b);
}
__device__ __forceinline__ int grayq(float r, float g, float b) {
    return gray1(u8q(r), u8q(g), u8q(b));
}
__device__ __forceinline__ int iabs(int v) { return v < 0 ? -v : v; }

__global__ __launch_bounds__(256, 4)
void csl_kernel(const float* __restrict__ pred, const float* __restrict__ tru,
                int2* __restrict__ ws) {
    const int b   = blockIdx.z;
    const int ty0 = blockIdx.y * TY;
    const int tx0 = blockIdx.x * TX;
    const int tid = threadIdx.x;

    __shared__ __align__(16) unsigned short gg[GR][GCS];
    __shared__ unsigned char mk[MR][MCS];
    __shared__ int wss[4], wse[4];

    const size_t chs = (size_t)Hn * Wn;
    const float* pb = pred + (size_t)b * 3 * chs;
    const float* tb = tru  + (size_t)b * 3 * chs;

    int Pk[8];  // per-pixel D | Su<<10 | St<<20

    // ---- Stage 1a: center 16x128, 8 px/thread, all 12 vec4 loads issued first ----
    {
        const int r0 = 2 + (tid >> 5), q0 = tid & 31;
        const int p1 = tid + 256;
        const int r1 = 2 + (p1 >> 5), q1 = p1 & 31;
        const size_t o0 = (size_t)(ty0 + r0 - 2) * Wn + tx0 + 4 * q0;
        const size_t o1 = (size_t)(ty0 + r1 - 2) * Wn + tx0 + 4 * q1;

        const float4 a0 = *(const float4*)(pb + o0);
        const float4 b0 = *(const float4*)(pb + chs + o0);
        const float4 c0 = *(const float4*)(pb + 2 * chs + o0);
        const float4 d0 = *(const float4*)(tb + o0);
        const float4 e0 = *(const float4*)(tb + chs + o0);
        const float4 f0 = *(const float4*)(tb + 2 * chs + o0);
        const float4 a1 = *(const float4*)(pb + o1);
        const float4 b1 = *(const float4*)(pb + chs + o1);
        const float4 c1 = *(const float4*)(pb + 2 * chs + o1);
        const float4 d1 = *(const float4*)(tb + o1);
        const float4 e1 = *(const float4*)(tb + chs + o1);
        const float4 f1 = *(const float4*)(tb + 2 * chs + o1);

        auto proc = [&](int r, int q, const float4& A, const float4& B,
                        const float4& C, const float4& D4, const float4& E,
                        const float4& F, int* pk) {
            const float* af = (const float*)&A; const float* bf = (const float*)&B;
            const float* cf = (const float*)&C; const float* df = (const float*)&D4;
            const float* ef = (const float*)&E; const float* ff = (const float*)&F;
            us4 gw;
            #pragma unroll
            for (int i = 0; i < 4; ++i) {
                const float pr = u8q(af[i]), pg = u8q(bf[i]), pl = u8q(cf[i]);
                const float tr_ = u8q(df[i]), tg = u8q(ef[i]), tl = u8q(ff[i]);
                const int gp = gray1(pr, pg, pl), gt = gray1(tr_, tg, tl);
                gw[i] = (unsigned short)(gp | (gt << 8));
                // exact in f32: operands are integers <= 765 < 2^24
                const float fD  = fabsf(pr - tr_) + fabsf(pg - tg) + fabsf(pl - tl);
                const float fSu = (pr + pg) + pl;
                const float fSt = (tr_ + tg) + tl;
                pk[i] = (int)fD | ((int)fSu << 10) | ((int)fSt << 20);
            }
            *(us4*)&gg[r][4 + 4 * q] = gw;
        };
        proc(r0, q0, a0, b0, c0, d0, e0, f0, Pk);
        proc(r1, q1, a1, b1, c1, d1, e1, f1, Pk + 4);
    }

    // ---- Stage 1b: halo rows 0,1,18,19 (vec4, gray only) ----
    if (tid < 128) {
        const int rh = tid >> 5;
        const int q = tid & 31;
        const int r = (rh < 2) ? rh : rh + 16;
        const int gy = reflect101(ty0 + r - 2, Hn);
        const size_t off = (size_t)gy * Wn + tx0 + 4 * q;
        const float4 A = *(const float4*)(pb + off);
        const float4 B = *(const float4*)(pb + chs + off);
        const float4 C = *(const float4*)(pb + 2 * chs + off);
        const float4 D4 = *(const float4*)(tb + off);
        const float4 E = *(const float4*)(tb + chs + off);
        const float4 F = *(const float4*)(tb + 2 * chs + off);
        const float* af = (const float*)&A; const float* bf = (const float*)&B;
        const float* cf = (const float*)&C; const float* df = (const float*)&D4;
        const float* ef = (const float*)&E; const float* ff = (const float*)&F;
        us4 gw;
        #pragma unroll
        for (int i = 0; i < 4; ++i) {
            const int gp = gray1(u8q(af[i]), u8q(bf[i]), u8q(cf[i]));
            const int gt = gray1(u8q(df[i]), u8q(ef[i]), u8q(ff[i]));
            gw[i] = (unsigned short)(gp | (gt << 8));
        }
        *(us4*)&gg[r][4 + 4 * q] = gw;
    } else if (tid < 168) {
        // ---- Stage 1c: halo cols (x_local -2,-1 -> cols 2,3; 128,129 -> 132,133) ----
        const int t = tid - 128;     // 0..39
        const int r = t >> 1;        // 0..19
        const int side = t & 1;
        const int gy = reflect101(ty0 + r - 2, Hn);
        const size_t rowo = (size_t)gy * Wn;
        if (side == 0) {
            if (tx0 > 0) {
                const size_t off = rowo + tx0 - 4;   // x_local -4..-1
                const float4 A = *(const float4*)(pb + off);
                const float4 B = *(const float4*)(pb + chs + off);
                const float4 C = *(const float4*)(pb + 2 * chs + off);
                const float4 D4 = *(const float4*)(tb + off);
                const float4 E = *(const float4*)(tb + chs + off);
                const float4 F = *(const float4*)(tb + 2 * chs + off);
                gg[r][2] = (unsigned short)(grayq(A.z, B.z, C.z) |
                                            (grayq(D4.z, E.z, F.z) << 8));
                gg[r][3] = (unsigned short)(grayq(A.w, B.w, C.w) |
                                            (grayq(D4.w, E.w, F.w) << 8));
            } else {
                const size_t o2 = rowo + 2, o1 = rowo + 1;   // reflect(-2)=2, reflect(-1)=1
                gg[r][2] = (unsigned short)(
                    grayq(pb[o2], pb[o2 + chs], pb[o2 + 2 * chs]) |
                    (grayq(tb[o2], tb[o2 + chs], tb[o2 + 2 * chs]) << 8));
                gg[r][3] = (unsigned short)(
                    grayq(pb[o1], pb[o1 + chs], pb[o1 + 2 * chs]) |
                    (grayq(tb[o1], tb[o1 + chs], tb[o1 + 2 * chs]) << 8));
            }
        } else {
            if (tx0 + TX < Wn) {
                const size_t off = rowo + tx0 + TX;  // x_local 128..131
                const float4 A = *(const float4*)(pb + off);
                const float4 B = *(const float4*)(pb + chs + off);
                const float4 C = *(const float4*)(pb + 2 * chs + off);
                const float4 D4 = *(const float4*)(tb + off);
                const float4 E = *(const float4*)(tb + chs + off);
                const float4 F = *(const float4*)(tb + 2 * chs + off);
                gg[r][132] = (unsigned short)(grayq(A.x, B.x, C.x) |
                                              (grayq(D4.x, E.x, F.x) << 8));
                gg[r][133] = (unsigned short)(grayq(A.y, B.y, C.y) |
                                              (grayq(D4.y, E.y, F.y) << 8));
            } else {
                const size_t oa = rowo + 510, ob = rowo + 509; // reflect(512),(513)
                gg[r][132] = (unsigned short)(
                    grayq(pb[oa], pb[oa + chs], pb[oa + 2 * chs]) |
                    (grayq(tb[oa], tb[oa + chs], tb[oa + 2 * chs]) << 8));
                gg[r][133] = (unsigned short)(
                    grayq(pb[ob], pb[ob + chs], pb[ob + 2 * chs]) |
                    (grayq(tb[ob], tb[ob + chs], tb[ob + 2 * chs]) << 8));
            }
        }
    }
    __syncthreads();

    // ---- Stage 2: int sobel on packed bytes, |sp-st| loss, 2-bit mask codes ----
    int accS = 0;
    auto sob4 = [&](int r, int q, bool center) {
        const int cb = 4 + 4 * q;
        const us4 U = *(const us4*)&gg[r][cb];
        const us4 M = *(const us4*)&gg[r + 1][cb];
        const us4 D = *(const us4*)&gg[r + 2][cb];
        const int ml = gg[r + 1][cb - 1];
        const int mr = gg[r + 1][cb + 4];
        const int m[6] = {ml, M.x, M.y, M.z, M.w, mr};
        const int u[4] = {U.x, U.y, U.z, U.w};
        const int d[4] = {D.x, D.y, D.z, D.w};
        unsigned cw = 0;
        #pragma unroll
        for (int i = 0; i < 4; ++i) {
            const int dxp = (m[i + 2] & 255) - (m[i] & 255);
            const int dyp = (d[i] & 255) - (u[i] & 255);
            const int dxt = (m[i + 2] >> 8) - (m[i] >> 8);
            const int dyt = (d[i] >> 8) - (u[i] >> 8);
            const int np = iabs(dxp) + iabs(dyp);
            const int nt = iabs(dxt) + iabs(dyt);
            const int hp = np >> 1, ht = nt >> 1;
            const int sp = hp + (np & hp & 1);   // RNE(np/2)
            const int st = ht + (nt & ht & 1);
            if (center) accS += iabs(sp - st);
            cw |= ((sp > 10 ? 1u : 0u) | (st > 10 ? 2u : 0u)) << (8 * i);
        }
        *(unsigned*)&mk[r][cb] = cw;
    };
    {
        const int r = tid >> 5, q = tid & 31;       // rows 0..7
        sob4(r, q, r >= 1);
    }
    {
        const int p1 = tid + 256;                    // rows 8..15, all center
        sob4(p1 >> 5, p1 & 31, true);
    }
    if (tid < 64) {
        const int p2 = tid + 512;                    // rows 16,17
        const int r = p2 >> 5;
        sob4(r, p2 & 31, r == 16);
    } else if (tid < 100) {
        // halo mask cols 3 (x=-1) and 132 (x=128)
        const int t = tid - 64;
        const int r = t >> 1;
        const int gc = (t & 1) ? 132 : 3;
        const int l = gg[r + 1][gc - 1], rr = gg[r + 1][gc + 1];
        const int uu = gg[r][gc], dd = gg[r + 2][gc];
        const int np = iabs((rr & 255) - (l & 255)) + iabs((dd & 255) - (uu & 255));
        const int nt = iabs((rr >> 8) - (l >> 8)) + iabs((dd >> 8) - (uu >> 8));
        const int hp = np >> 1, ht = nt >> 1;
        const int sp = hp + (np & hp & 1);
        const int st = ht + (nt & ht & 1);
        mk[r][gc] = (unsigned char)((sp > 10 ? 1u : 0u) | (st > 10 ? 2u : 0u));
    }
    __syncthreads();

    // ---- Stage 3: keep = OR over 3x3 codes; edge loss in int ----
    int accE = 0;
    #pragma unroll
    for (int j = 0; j < 2; ++j) {
        const int pos = tid + 256 * j;
        const int py = pos >> 5;       // 0..15, matches stage-1a slot j
        const int q = pos & 31;
        const int cb = 4 + 4 * q;
        unsigned Lo = 0, Co = 0, Ro = 0;
        #pragma unroll
        for (int d = 0; d < 3; ++d) {
            Lo |= *(const unsigned*)&mk[py + d][cb - 4];
            Co |= *(const unsigned*)&mk[py + d][cb];
            Ro |= *(const unsigned*)&mk[py + d][cb + 4];
        }
        unsigned long long w = (unsigned long long)(Lo >> 24) |
                               ((unsigned long long)Co << 8) |
                               ((unsigned long long)(Ro & 0xFFu) << 40);
        unsigned long long t3 = w | (w >> 8) | (w >> 16);
        const int* Pp = &Pk[4 * j];
        #pragma unroll
        for (int i = 0; i < 4; ++i) {
            const unsigned code = (unsigned)(t3 >> (8 * i)) & 3u;
            const int D = Pp[i] & 1023;
            const int Su = (Pp[i] >> 10) & 1023;
            const int St = Pp[i] >> 20;
            const int s1 = (code & 2u) ? D : Su;
            const int s0 = (code & 2u) ? St : 0;
            accE += (code & 1u) ? s1 : s0;
        }
    }

    // ---- Block reduction -> uncontended partial-sum store ----
    #pragma unroll
    for (int off = 32; off > 0; off >>= 1) {
        accS += __shfl_down(accS, off, 64);
        accE += __shfl_down(accE, off, 64);
    }
    const int wave = tid >> 6, lane = tid & 63;
    if (lane == 0) { wss[wave] = accS; wse[wave] = accE; }
    __syncthreads();
    if (tid == 0) {
        const int ts = (wss[0] + wss[1]) + (wss[2] + wss[3]);
        const int te = (wse[0] + wse[1]) + (wse[2] + wse[3]);
        const int bid = (blockIdx.z * gridDim.y + blockIdx.y) * gridDim.x + blockIdx.x;
        ws[bid] = make_int2(ts, te);
    }
}

__global__ __launch_bounds__(256)
void reduce_kernel(const int2* __restrict__ ws, float* __restrict__ out) {
    const int tid = threadIdx.x;
    int s = 0, e = 0;
    for (int i = tid; i < NBLK; i += 256) {
        const int2 v = ws[i];
        s += v.x; e += v.y;
    }
    double ds = (double)s, de = (double)e;
    #pragma unroll
    for (int off = 32; off > 0; off >>= 1) {
        ds += __shfl_down(ds, off, 64);
        de += __shfl_down(de, off, 64);
    }
    __shared__ double rs[4], re[4];
    const int wave = tid >> 6, lane = tid & 63;
    if (lane == 0) { rs[wave] = ds; re[wave] = de; }
    __syncthreads();
    if (tid == 0) {
        const double ts = (rs[0] + rs[1]) + (rs[2] + rs[3]);
        const double te = (re[0] + re[1]) + (re[2] + re[3]);
        const float inv_s = 1.0f / (255.0f * (float)Bn * (float)Hn * (float)Wn);
        out[0] = (float)ts * inv_s;
        out[1] = (float)te * (inv_s / 3.0f);
    }
}

extern "C" void kernel_launch(void* const* d_in, const int* in_sizes, int n_in,
                              void* d_out, int out_size, void* d_ws, size_t ws_size,
                              hipStream_t stream) {
    const float* pred = (const float*)d_in[0];
    const float* tru  = (const float*)d_in[1];
    float* out = (float*)d_out;
    int2* ws = (int2*)d_ws;   // NBLK int2 partials = 16 KB

    dim3 grid(Wn / TX, Hn / TY, Bn);  // 4 x 32 x 16 = 2048 blocks
    csl_kernel<<<grid, 256, 0, stream>>>(pred, tru, ws);
    reduce_kernel<<<1, 256, 0, stream>>>(ws, out);
}